// Round 3
// baseline (1463.639 us; speedup 1.0000x reference)
//
#include <hip/hip_runtime.h>
#include <hip/hip_bf16.h>
#include <hip/hip_cooperative_groups.h>
#include <math.h>

namespace cg = cooperative_groups;

typedef __bf16 bf16;
typedef __bf16 v8bf __attribute__((ext_vector_type(8)));
typedef __bf16 v4bfv __attribute__((ext_vector_type(4)));
typedef float  v4f  __attribute__((ext_vector_type(4)));

#define B_   128
#define KK_  49
#define D_   512
#define E_   256
#define V_   10000
#define T_   20
#define NG_  2048   // 4*D
#define XK_  768    // E+D
#define VPAD 10112  // 79*128 (Wp rows padded)
#define NP_  128    // padded small-N

#define GLOAD_LDS16(gp, lp) \
    __builtin_amdgcn_global_load_lds((const __attribute__((address_space(1))) void*)(gp), \
                                     (__attribute__((address_space(3))) void*)(lp), 16, 0, 0)

__device__ inline v4bfv cvt4(float4 v) {
    v4bfv o; o[0] = (bf16)v.x; o[1] = (bf16)v.y; o[2] = (bf16)v.z; o[3] = (bf16)v.w;
    return o;
}

// ---------------------------------------------------------------------------
// Prep: fp32->bf16 conversions (float4-vectorized), padding, gather of LSTM
// input rows, packed init weights/biases.
// ---------------------------------------------------------------------------
__global__ void prep_kernel(
    const float* __restrict__ spatial, const float* __restrict__ gfeat,
    const int* __restrict__ caps, const float* __restrict__ emb,
    const float* __restrict__ W_init_h, const float* __restrict__ b_init_h,
    const float* __restrict__ W_init_m, const float* __restrict__ b_init_m,
    const float* __restrict__ W_ih, const float* __restrict__ b_ih,
    const float* __restrict__ W_hh, const float* __restrict__ b_hh,
    const float* __restrict__ Wv, const float* __restrict__ bv,
    const float* __restrict__ Wg, const float* __restrict__ bg,
    const float* __restrict__ Wp,
    bf16* __restrict__ Wp_b, bf16* __restrict__ Whh_b, bf16* __restrict__ Wih_b,
    bf16* __restrict__ Xin_b, bf16* __restrict__ Sp_b,
    bf16* __restrict__ Wv_b, bf16* __restrict__ Wg_b,
    bf16* __restrict__ Winit2_b, bf16* __restrict__ Gf_b,
    float* __restrict__ bias_comb, float* __restrict__ bias_init,
    float* __restrict__ bv_pad, float* __restrict__ bg_pad)
{
    const int stride = gridDim.x * blockDim.x;
    const int tid0 = blockIdx.x * blockDim.x + threadIdx.x;
    const float4 z4 = make_float4(0.f, 0.f, 0.f, 0.f);

    // Wp -> bf16, padded to VPAD rows
    for (int i4 = tid0; i4 < VPAD * D_ / 4; i4 += stride) {
        int row = i4 >> 7;
        float4 v = (row < V_) ? ((const float4*)Wp)[i4] : z4;
        ((v4bfv*)Wp_b)[i4] = cvt4(v);
    }
    // W_hh -> bf16
    for (int i4 = tid0; i4 < NG_ * D_ / 4; i4 += stride)
        ((v4bfv*)Whh_b)[i4] = cvt4(((const float4*)W_hh)[i4]);
    // W_ih -> bf16
    for (int i4 = tid0; i4 < NG_ * XK_ / 4; i4 += stride)
        ((v4bfv*)Wih_b)[i4] = cvt4(((const float4*)W_ih)[i4]);
    // Xin rows r = t*128+b : [emb[captions[b,t]], global_feats[b]]
    for (int i4 = tid0; i4 < T_ * B_ * XK_ / 4; i4 += stride) {
        int r = i4 / (XK_ / 4), c4 = i4 - r * (XK_ / 4);
        int c = c4 * 4;
        int t = r >> 7, b = r & 127;
        float4 v;
        if (c < E_) v = *(const float4*)&emb[(long)caps[b * T_ + t] * E_ + c];
        else        v = *(const float4*)&gfeat[(long)b * D_ + (c - E_)];
        ((v4bfv*)Xin_b)[i4] = cvt4(v);
    }
    // spatial -> bf16 (flattened [B*K, D])
    for (int i4 = tid0; i4 < B_ * KK_ * D_ / 4; i4 += stride)
        ((v4bfv*)Sp_b)[i4] = cvt4(((const float4*)spatial)[i4]);
    // Wv / Wg padded to 128 rows
    for (int i4 = tid0; i4 < NP_ * D_ / 4; i4 += stride) {
        int row = i4 >> 7;
        ((v4bfv*)Wv_b)[i4] = cvt4((row < KK_) ? ((const float4*)Wv)[i4] : z4);
        ((v4bfv*)Wg_b)[i4] = cvt4((row < KK_) ? ((const float4*)Wg)[i4] : z4);
    }
    // packed [W_init_h; W_init_m]  (1024 x 512)
    for (int i4 = tid0; i4 < 2 * D_ * D_ / 4; i4 += stride) {
        int row = i4 >> 7;
        float4 v = (row < D_) ? ((const float4*)W_init_h)[i4]
                              : ((const float4*)W_init_m)[i4 - D_ * (D_ / 4)];
        ((v4bfv*)Winit2_b)[i4] = cvt4(v);
    }
    // global_feats -> bf16
    for (int i4 = tid0; i4 < B_ * D_ / 4; i4 += stride)
        ((v4bfv*)Gf_b)[i4] = cvt4(((const float4*)gfeat)[i4]);
    // combined gate bias
    for (int i = tid0; i < NG_; i += stride) bias_comb[i] = b_ih[i] + b_hh[i];
    // packed init bias
    for (int i = tid0; i < 2 * D_; i += stride)
        bias_init[i] = (i < D_) ? b_init_h[i] : b_init_m[i - D_];
    // padded small biases
    for (int i = tid0; i < NP_; i += stride) {
        bv_pad[i] = (i < KK_) ? bv[i] : 0.f;
        bg_pad[i] = (i < KK_) ? bg[i] : 0.f;
    }
}

// ---------------------------------------------------------------------------
// Generic bf16 MFMA GEMM, BK=64: C[M,N] = A[M,K] @ Bm[N,K]^T + bias[n]
// 128x128 tile, 4 waves, each 64x64 (4x4 of 16x16x32 MFMA), two 32-wide
// k-panels per LDS buffer (m97 row layout inside each panel).
// blockIdx.x = m-tile (fastest, B-tile L2 reuse), blockIdx.y = n-tile.
// OUTMODE: 0=f32, 1=bf16, 2=logits(masked f32, n<n_real, stride out_stride),
//          3=split: n<D_ -> bf16 Cout[m*D_+n], else f32 Cout2[m*D_+n-D_]
// ---------------------------------------------------------------------------
template <int OUTMODE>
__global__ __launch_bounds__(256) void gemm_bt(
    const bf16* __restrict__ A, const bf16* __restrict__ Bm,
    const float* __restrict__ bias, void* __restrict__ Cout, void* __restrict__ Cout2,
    int M, int N, int K, int out_stride, int n_real, const int* __restrict__ lengths)
{
    __shared__ bf16 As[2 * 128 * 32];   // 16 KB: panel h=0,1
    __shared__ bf16 Bs[2 * 128 * 32];
    const int m0 = blockIdx.x * 128, n0 = blockIdx.y * 128;
    const int tid = threadIdx.x;
    const int w = tid >> 6, l = tid & 63;
    const int wm = (w >> 1) * 64, wn = (w & 1) * 64;
    const int lr = l & 15, lq = l >> 4;

    v4f acc[4][4] = {};

    for (int k0 = 0; k0 < K; k0 += 64) {
        __syncthreads();
        #pragma unroll
        for (int c = 0; c < 4; c++) {
            int u = c * 256 + tid;
            int h = u >> 9, v = u & 511;
            int row = v >> 2, kc = (v & 3) * 8;
            int u0 = c * 256 + (tid & ~63);   // wave-uniform LDS base
            GLOAD_LDS16(&A[(long)(m0 + row) * K + k0 + h * 32 + kc], &As[u0 * 8]);
            GLOAD_LDS16(&Bm[(long)(n0 + row) * K + k0 + h * 32 + kc], &Bs[u0 * 8]);
        }
        __syncthreads();
        #pragma unroll
        for (int h = 0; h < 2; h++) {
            v8bf af[4], bfv[4];
            #pragma unroll
            for (int s = 0; s < 4; s++) {
                af[s]  = *(const v8bf*)&As[h * 4096 + (wm + s * 16 + lr) * 32 + lq * 8];
                bfv[s] = *(const v8bf*)&Bs[h * 4096 + (wn + s * 16 + lr) * 32 + lq * 8];
            }
            #pragma unroll
            for (int i = 0; i < 4; i++)
                #pragma unroll
                for (int j = 0; j < 4; j++)
                    acc[i][j] = __builtin_amdgcn_mfma_f32_16x16x32_bf16(af[i], bfv[j], acc[i][j], 0, 0, 0);
        }
    }

    #pragma unroll
    for (int i = 0; i < 4; i++)
        #pragma unroll
        for (int j = 0; j < 4; j++)
            #pragma unroll
            for (int r = 0; r < 4; r++) {
                int m = m0 + wm + i * 16 + lq * 4 + r;
                int n = n0 + wn + j * 16 + lr;
                float v = acc[i][j][r];
                if (OUTMODE == 2) {
                    if (n < n_real) {
                        int t = m % T_, b = m / T_;
                        float o = (t < lengths[b]) ? (v + bias[n]) : 0.f;
                        ((float*)Cout)[(long)m * out_stride + n] = o;
                    }
                } else if (OUTMODE == 3) {
                    if (n < D_) ((bf16*)Cout)[(long)m * D_ + n] = (bf16)(v + bias[n]);
                    else ((float*)Cout2)[(long)m * D_ + n - D_] = v + bias[n];
                } else if (OUTMODE == 1) {
                    ((bf16*)Cout)[(long)m * out_stride + n] = (bf16)(v + bias[n]);
                } else {
                    ((float*)Cout)[(long)m * out_stride + n] = v + bias[n];
                }
            }
}

// ---------------------------------------------------------------------------
// Fused LSTM recurrence: one cooperative kernel runs all T steps.
// 256 blocks x 256 thr. Block owns (16 b) x (16 j) x (4 gates) forever:
//   - W_hh slice (64 rows x 512) in LDS: 14 k-panels (56 KB) + panels 14,15
//     held in registers per wave.
//   - m and h state for (b,j) live in the owning thread's registers.
//   - H sequence buffer Hb16[t] is the step ping-pong (also feeds attention).
// Per step: wave w computes gate w's 16x16 tile (16 MFMAs, A from global H,
// B from LDS), LDS exchange, pointwise, store H[t+1], grid.sync().
// ---------------------------------------------------------------------------
__global__ __launch_bounds__(256) void lstm_fused(
    bf16* __restrict__ Hb16, const bf16* __restrict__ Whh_b,
    const float* __restrict__ Xpre, const float* __restrict__ mbuf,
    const int* __restrict__ lengths)
{
    cg::grid_group gg = cg::this_grid();
    const int blk = blockIdx.x;
    const int bt = blk & 7, jt = blk >> 3;   // 8 b-tiles x 32 j-tiles
    const int b0 = bt * 16, j0 = jt * 16;
    const int tid = threadIdx.x;
    const int w = tid >> 6, l = tid & 63;
    const int lr = l & 15, lq = l >> 4;

    __shared__ bf16 Bl[14 * 64 * 32];        // 56 KB: 14 k-panels x 64 rows x 32
    __shared__ float g4[4][16][16];          // 4 KB gate exchange

    // one-time stage of W_hh slice panels 0..13 (rows: gate*16 + jr)
    for (int c = tid; c < 14 * 256; c += 256) {
        int p = c >> 8, q = c & 255;
        int r = q >> 2, kc = (q & 3) * 8;
        int gate = r >> 4, jr = r & 15;
        ((int4*)Bl)[c] = *(const int4*)&Whh_b[(long)(gate * D_ + j0 + jr) * D_ + p * 32 + kc];
    }
    // panels 14,15 in registers (per wave: gate w, row j0+lr)
    const bf16* wrow = Whh_b + (long)(w * D_ + j0 + lr) * D_;
    v8bf bv14 = *(const v8bf*)&wrow[14 * 32 + lq * 8];
    v8bf bv15 = *(const v8bf*)&wrow[15 * 32 + lq * 8];

    // per-thread recurrent state
    const int bi = tid >> 4, jj = tid & 15;
    const int bg = b0 + bi, jg = j0 + jj;
    const long hidx = (long)bg * D_ + jg;
    float m_st = mbuf[hidx];
    float h_st = (float)Hb16[hidx];          // h0
    const int len = lengths[bg];
    __syncthreads();

    for (int t = 0; t < T_; t++) {
        const bf16* Arow = Hb16 + (long)t * B_ * D_ + (long)(b0 + lr) * D_;
        v8bf af[16];
        #pragma unroll
        for (int p = 0; p < 16; p++)
            af[p] = *(const v8bf*)&Arow[p * 32 + lq * 8];
        v4f acc = {};
        #pragma unroll
        for (int p = 0; p < 14; p++) {
            v8bf bfv = *(const v8bf*)&Bl[p * 2048 + (w * 16 + lr) * 32 + lq * 8];
            acc = __builtin_amdgcn_mfma_f32_16x16x32_bf16(af[p], bfv, acc, 0, 0, 0);
        }
        acc = __builtin_amdgcn_mfma_f32_16x16x32_bf16(af[14], bv14, acc, 0, 0, 0);
        acc = __builtin_amdgcn_mfma_f32_16x16x32_bf16(af[15], bv15, acc, 0, 0, 0);
        #pragma unroll
        for (int r = 0; r < 4; r++)
            g4[w][lq * 4 + r][lr] = acc[r];
        __syncthreads();

        const float* xp = Xpre + (long)t * B_ * NG_ + (long)bg * NG_ + jg;
        float gi = g4[0][bi][jj] + xp[0];
        float gf = g4[1][bi][jj] + xp[D_];
        float gc = g4[2][bi][jj] + xp[2 * D_];
        float go = g4[3][bi][jj] + xp[3 * D_];
        gi = 1.f / (1.f + expf(-gi));
        gf = 1.f / (1.f + expf(-gf));
        gc = tanhf(gc);
        go = 1.f / (1.f + expf(-go));
        float m_new = gf * m_st + gi * gc;
        float h_new = go * tanhf(m_new);
        bool active = t < len;
        m_st = active ? m_new : m_st;
        h_st = active ? h_new : h_st;
        Hb16[(long)(t + 1) * B_ * D_ + hidx] = (bf16)h_st;
        __threadfence();
        gg.sync();
    }
}

// ---------------------------------------------------------------------------
// Attention + context. 4 waves/block; waves share b (spatial L1 reuse), each
// wave owns one t. ctx[b*T+t] = softmax_k(z) @ spatial[b] + h_t  (bf16).
// ---------------------------------------------------------------------------
__global__ __launch_bounds__(256) void attn_kernel(
    const bf16* __restrict__ Hb16, const float* __restrict__ g_all,
    const float* __restrict__ Vproj, const float* __restrict__ wh,
    const float* __restrict__ bh_att, const float* __restrict__ spatial,
    bf16* __restrict__ ctx)
{
    const int w = threadIdx.x >> 6, l = threadIdx.x & 63;
    const int b = blockIdx.x / 5, tg = blockIdx.x % 5;
    const int t = tg * 4 + w;
    const int r = t * 128 + b;            // row in g_all
    __shared__ float sg[4][64], sal[4][64], swh[64];

    if (w == 0) swh[l] = (l < KK_) ? wh[l] : 0.f;
    sg[w][l] = (l < KK_) ? g_all[(long)r * NP_ + l] : 0.f;
    __syncthreads();

    float z = -1e30f;
    if (l < KK_) {
        const float* vp = Vproj + (long)(b * KK_ + l) * NP_;
        float a = 0.f;
        for (int j = 0; j < KK_; j++)
            a += swh[j] * tanhf(vp[j] + sg[w][j]);
        z = a + bh_att[0];
    }
    float mx = z;
    #pragma unroll
    for (int o = 32; o > 0; o >>= 1) mx = fmaxf(mx, __shfl_xor(mx, o));
    float e = (l < KK_) ? expf(z - mx) : 0.f;
    float sm = e;
    #pragma unroll
    for (int o = 32; o > 0; o >>= 1) sm += __shfl_xor(sm, o);
    sal[w][l] = e / sm;
    __syncthreads();

    const bf16* hrow = Hb16 + (long)(t + 1) * B_ * D_ + (long)b * D_;
    const float* sp = spatial + (long)b * KK_ * D_;
    bf16* crow = ctx + (long)(b * T_ + t) * D_;
    for (int d = l; d < D_; d += 64) {
        float c = 0.f;
        for (int k = 0; k < KK_; k++)
            c += sal[w][k] * sp[k * D_ + d];
        crow[d] = (bf16)(c + (float)hrow[d]);
    }
}

// ---------------------------------------------------------------------------
extern "C" void kernel_launch(void* const* d_in, const int* in_sizes, int n_in,
                              void* d_out, int out_size, void* d_ws, size_t ws_size,
                              hipStream_t stream)
{
    const float* spatial  = (const float*)d_in[0];
    const float* gfeat    = (const float*)d_in[1];
    const int*   caps     = (const int*)d_in[2];
    const int*   lengths  = (const int*)d_in[3];
    const float* emb      = (const float*)d_in[4];
    const float* W_init_h = (const float*)d_in[5];
    const float* b_init_h = (const float*)d_in[6];
    const float* W_init_m = (const float*)d_in[7];
    const float* b_init_m = (const float*)d_in[8];
    const float* W_ih     = (const float*)d_in[9];
    const float* b_ih     = (const float*)d_in[10];
    const float* W_hh     = (const float*)d_in[11];
    const float* b_hh     = (const float*)d_in[12];
    const float* Wv       = (const float*)d_in[13];
    const float* bv       = (const float*)d_in[14];
    const float* Wg       = (const float*)d_in[15];
    const float* bg       = (const float*)d_in[16];
    const float* wh       = (const float*)d_in[17];
    const float* bh_att   = (const float*)d_in[18];
    const float* Wp       = (const float*)d_in[19];
    const float* bp       = (const float*)d_in[20];
    float* out = (float*)d_out;

    char* ws = (char*)d_ws;
    size_t off = 0;
    auto alloc = [&](size_t bytes) -> void* {
        off = (off + 255) & ~(size_t)255;
        void* p = ws + off;
        off += bytes;
        return p;
    };

    bf16* Wp_b    = (bf16*)alloc((size_t)VPAD * D_ * 2);
    bf16* Whh_b   = (bf16*)alloc((size_t)NG_ * D_ * 2);
    bf16* Wih_b   = (bf16*)alloc((size_t)NG_ * XK_ * 2);
    bf16* Xin_b   = (bf16*)alloc((size_t)T_ * B_ * XK_ * 2);
    bf16* Sp_b    = (bf16*)alloc((size_t)B_ * KK_ * D_ * 2);
    bf16* Wv_b    = (bf16*)alloc((size_t)NP_ * D_ * 2);
    bf16* Wg_b    = (bf16*)alloc((size_t)NP_ * D_ * 2);
    bf16* Winit2_b= (bf16*)alloc((size_t)2 * D_ * D_ * 2);
    bf16* Gf_b    = (bf16*)alloc((size_t)B_ * D_ * 2);
    float* bias_comb = (float*)alloc(NG_ * 4);
    float* bias_init = (float*)alloc(2 * D_ * 4);
    float* bv_pad    = (float*)alloc(NP_ * 4);
    float* bg_pad    = (float*)alloc(NP_ * 4);
    bf16* Hb16    = (bf16*)alloc((size_t)(T_ + 1) * B_ * D_ * 2);
    float* mbuf   = (float*)alloc((size_t)B_ * D_ * 4);
    float* Xpre   = (float*)alloc((size_t)T_ * B_ * NG_ * 4);
    float* VprojW = (float*)alloc((size_t)B_ * KK_ * NP_ * 4);
    float* g_allW = (float*)alloc((size_t)T_ * B_ * NP_ * 4);
    bf16* ctx     = (bf16*)alloc((size_t)T_ * B_ * D_ * 2);

    // 1. prep / conversions
    prep_kernel<<<1024, 256, 0, stream>>>(
        spatial, gfeat, caps, emb, W_init_h, b_init_h, W_init_m, b_init_m,
        W_ih, b_ih, W_hh, b_hh, Wv, bv, Wg, bg, Wp,
        Wp_b, Whh_b, Wih_b, Xin_b, Sp_b, Wv_b, Wg_b, Winit2_b, Gf_b,
        bias_comb, bias_init, bv_pad, bg_pad);

    // 2. h0 (bf16 -> Hb16[0]) and m0 (f32 -> mbuf) in one GEMM
    gemm_bt<3><<<dim3(1, 8), 256, 0, stream>>>(Gf_b, Winit2_b, bias_init,
                                               Hb16, mbuf, B_, 2 * D_, D_, 0, 0, nullptr);

    // 3. V_proj = spatial @ Wv^T + bv  -> [B*K, 128] f32
    gemm_bt<0><<<dim3((B_ * KK_) / 128, 1), 256, 0, stream>>>(
        Sp_b, Wv_b, bv_pad, VprojW, nullptr, B_ * KK_, NP_, D_, NP_, 0, nullptr);

    // 4. Xpre = Xin @ W_ih^T + (b_ih + b_hh)  -> [T*B, 2048] f32
    gemm_bt<0><<<dim3((T_ * B_) / 128, NG_ / 128), 256, 0, stream>>>(
        Xin_b, Wih_b, bias_comb, Xpre, nullptr, T_ * B_, NG_, XK_, NG_, 0, nullptr);

    // 5. all 20 LSTM steps in one cooperative kernel
    {
        void* args[] = { (void*)&Hb16, (void*)&Whh_b, (void*)&Xpre,
                         (void*)&mbuf, (void*)&lengths };
        hipLaunchCooperativeKernel((void*)lstm_fused, dim3(256), dim3(256),
                                   args, 0, stream);
    }

    // 6. g_all = H[1..T] @ Wg^T + bg  -> [T*B, 128] f32
    gemm_bt<0><<<dim3((T_ * B_) / 128, 1), 256, 0, stream>>>(
        Hb16 + (size_t)B_ * D_, Wg_b, bg_pad, g_allW, nullptr, T_ * B_, NP_, D_, NP_, 0, nullptr);

    // 7. attention + ctx = c + h  (bf16, rows b*T+t)
    attn_kernel<<<B_ * 5, 256, 0, stream>>>(Hb16, g_allW, VprojW, wh, bh_att,
                                            spatial, ctx);

    // 8. logits = ctx @ Wp^T + bp, masked, -> d_out [B*T, V]
    gemm_bt<2><<<dim3((T_ * B_) / 128, VPAD / 128), 256, 0, stream>>>(
        ctx, Wp_b, bp, out, nullptr, T_ * B_, VPAD, D_, V_, V_, lengths);
}

// Round 4
// 861.891 us; speedup vs baseline: 1.6982x; 1.6982x over previous
//
#include <hip/hip_runtime.h>
#include <hip/hip_bf16.h>
#include <math.h>

typedef __bf16 bf16;
typedef __bf16 v8bf __attribute__((ext_vector_type(8)));
typedef __bf16 v4bfv __attribute__((ext_vector_type(4)));
typedef float  v4f  __attribute__((ext_vector_type(4)));

#define B_   128
#define KK_  49
#define D_   512
#define E_   256
#define V_   10000
#define T_   20
#define NG_  2048   // 4*D
#define XK_  768    // E+D
#define VPAD 10240  // 40*256 (Wp rows padded for 256-wide n-tiles)
#define NP_  128    // padded small-N

#define GLOAD_LDS16(gp, lp) \
    __builtin_amdgcn_global_load_lds((const __attribute__((address_space(1))) void*)(gp), \
                                     (__attribute__((address_space(3))) void*)(lp), 16, 0, 0)

__device__ inline v4bfv cvt4(float4 v) {
    v4bfv o; o[0] = (bf16)v.x; o[1] = (bf16)v.y; o[2] = (bf16)v.z; o[3] = (bf16)v.w;
    return o;
}

// ---------------------------------------------------------------------------
// Prep: fp32->bf16 conversions (float4-vectorized), padding, gather of LSTM
// input rows, packed init weights/biases.
// ---------------------------------------------------------------------------
__global__ void prep_kernel(
    const float* __restrict__ spatial, const float* __restrict__ gfeat,
    const int* __restrict__ caps, const float* __restrict__ emb,
    const float* __restrict__ W_init_h, const float* __restrict__ b_init_h,
    const float* __restrict__ W_init_m, const float* __restrict__ b_init_m,
    const float* __restrict__ W_ih, const float* __restrict__ b_ih,
    const float* __restrict__ W_hh, const float* __restrict__ b_hh,
    const float* __restrict__ Wv, const float* __restrict__ bv,
    const float* __restrict__ Wg, const float* __restrict__ bg,
    const float* __restrict__ Wp,
    bf16* __restrict__ Wp_b, bf16* __restrict__ Whh_b, bf16* __restrict__ Wih_b,
    bf16* __restrict__ Xin_b, bf16* __restrict__ Sp_b,
    bf16* __restrict__ Wv_b, bf16* __restrict__ Wg_b,
    bf16* __restrict__ Winit2_b, bf16* __restrict__ Gf_b,
    float* __restrict__ bias_comb, float* __restrict__ bias_init,
    float* __restrict__ bv_pad, float* __restrict__ bg_pad)
{
    const int stride = gridDim.x * blockDim.x;
    const int tid0 = blockIdx.x * blockDim.x + threadIdx.x;
    const float4 z4 = make_float4(0.f, 0.f, 0.f, 0.f);

    // Wp -> bf16, padded to VPAD rows
    for (int i4 = tid0; i4 < VPAD * D_ / 4; i4 += stride) {
        int row = i4 >> 7;
        float4 v = (row < V_) ? ((const float4*)Wp)[i4] : z4;
        ((v4bfv*)Wp_b)[i4] = cvt4(v);
    }
    // W_hh -> bf16
    for (int i4 = tid0; i4 < NG_ * D_ / 4; i4 += stride)
        ((v4bfv*)Whh_b)[i4] = cvt4(((const float4*)W_hh)[i4]);
    // W_ih -> bf16
    for (int i4 = tid0; i4 < NG_ * XK_ / 4; i4 += stride)
        ((v4bfv*)Wih_b)[i4] = cvt4(((const float4*)W_ih)[i4]);
    // Xin rows r = t*128+b : [emb[captions[b,t]], global_feats[b]]
    for (int i4 = tid0; i4 < T_ * B_ * XK_ / 4; i4 += stride) {
        int r = i4 / (XK_ / 4), c4 = i4 - r * (XK_ / 4);
        int c = c4 * 4;
        int t = r >> 7, b = r & 127;
        float4 v;
        if (c < E_) v = *(const float4*)&emb[(long)caps[b * T_ + t] * E_ + c];
        else        v = *(const float4*)&gfeat[(long)b * D_ + (c - E_)];
        ((v4bfv*)Xin_b)[i4] = cvt4(v);
    }
    // spatial -> bf16 (flattened [B*K, D])
    for (int i4 = tid0; i4 < B_ * KK_ * D_ / 4; i4 += stride)
        ((v4bfv*)Sp_b)[i4] = cvt4(((const float4*)spatial)[i4]);
    // Wv / Wg padded to 128 rows
    for (int i4 = tid0; i4 < NP_ * D_ / 4; i4 += stride) {
        int row = i4 >> 7;
        ((v4bfv*)Wv_b)[i4] = cvt4((row < KK_) ? ((const float4*)Wv)[i4] : z4);
        ((v4bfv*)Wg_b)[i4] = cvt4((row < KK_) ? ((const float4*)Wg)[i4] : z4);
    }
    // packed [W_init_h; W_init_m]  (1024 x 512)
    for (int i4 = tid0; i4 < 2 * D_ * D_ / 4; i4 += stride) {
        int row = i4 >> 7;
        float4 v = (row < D_) ? ((const float4*)W_init_h)[i4]
                              : ((const float4*)W_init_m)[i4 - D_ * (D_ / 4)];
        ((v4bfv*)Winit2_b)[i4] = cvt4(v);
    }
    // global_feats -> bf16
    for (int i4 = tid0; i4 < B_ * D_ / 4; i4 += stride)
        ((v4bfv*)Gf_b)[i4] = cvt4(((const float4*)gfeat)[i4]);
    // combined gate bias
    for (int i = tid0; i < NG_; i += stride) bias_comb[i] = b_ih[i] + b_hh[i];
    // packed init bias
    for (int i = tid0; i < 2 * D_; i += stride)
        bias_init[i] = (i < D_) ? b_init_h[i] : b_init_m[i - D_];
    // padded small biases
    for (int i = tid0; i < NP_; i += stride) {
        bv_pad[i] = (i < KK_) ? bv[i] : 0.f;
        bg_pad[i] = (i < KK_) ? bg[i] : 0.f;
    }
}

// ---------------------------------------------------------------------------
// Generic bf16 MFMA GEMM, BK=64: C[M,N] = A[M,K] @ Bm[N,K]^T + bias[n]
// 128x128 tile, 4 waves, each 64x64 (4x4 of 16x16x32 MFMA).
// OUTMODE: 0=f32, 3=split: n<D_ -> bf16 Cout[m*D_+n], else f32 Cout2[m*D_+n-D_]
// ---------------------------------------------------------------------------
template <int OUTMODE>
__global__ __launch_bounds__(256) void gemm_bt(
    const bf16* __restrict__ A, const bf16* __restrict__ Bm,
    const float* __restrict__ bias, void* __restrict__ Cout, void* __restrict__ Cout2,
    int M, int N, int K, int out_stride)
{
    __shared__ bf16 As[2 * 128 * 32];   // 16 KB: panel h=0,1
    __shared__ bf16 Bs[2 * 128 * 32];
    const int m0 = blockIdx.x * 128, n0 = blockIdx.y * 128;
    const int tid = threadIdx.x;
    const int w = tid >> 6, l = tid & 63;
    const int wm = (w >> 1) * 64, wn = (w & 1) * 64;
    const int lr = l & 15, lq = l >> 4;

    v4f acc[4][4] = {};

    for (int k0 = 0; k0 < K; k0 += 64) {
        __syncthreads();
        #pragma unroll
        for (int c = 0; c < 4; c++) {
            int u = c * 256 + tid;
            int h = u >> 9, v = u & 511;
            int row = v >> 2, kc = (v & 3) * 8;
            int u0 = c * 256 + (tid & ~63);   // wave-uniform LDS base
            GLOAD_LDS16(&A[(long)(m0 + row) * K + k0 + h * 32 + kc], &As[u0 * 8]);
            GLOAD_LDS16(&Bm[(long)(n0 + row) * K + k0 + h * 32 + kc], &Bs[u0 * 8]);
        }
        __syncthreads();
        #pragma unroll
        for (int h = 0; h < 2; h++) {
            v8bf af[4], bfv[4];
            #pragma unroll
            for (int s = 0; s < 4; s++) {
                af[s]  = *(const v8bf*)&As[h * 4096 + (wm + s * 16 + lr) * 32 + lq * 8];
                bfv[s] = *(const v8bf*)&Bs[h * 4096 + (wn + s * 16 + lr) * 32 + lq * 8];
            }
            #pragma unroll
            for (int i = 0; i < 4; i++)
                #pragma unroll
                for (int j = 0; j < 4; j++)
                    acc[i][j] = __builtin_amdgcn_mfma_f32_16x16x32_bf16(af[i], bfv[j], acc[i][j], 0, 0, 0);
        }
    }

    #pragma unroll
    for (int i = 0; i < 4; i++)
        #pragma unroll
        for (int j = 0; j < 4; j++)
            #pragma unroll
            for (int r = 0; r < 4; r++) {
                int m = m0 + wm + i * 16 + lq * 4 + r;
                int n = n0 + wn + j * 16 + lr;
                float v = acc[i][j][r];
                if (OUTMODE == 3) {
                    if (n < D_) ((bf16*)Cout)[(long)m * D_ + n] = (bf16)(v + bias[n]);
                    else ((float*)Cout2)[(long)m * D_ + n - D_] = v + bias[n];
                } else {
                    ((float*)Cout)[(long)m * out_stride + n] = v + bias[n];
                }
            }
}

// ---------------------------------------------------------------------------
// Logits GEMM: 128x256 tile, BK=64, 64 MFMAs per barrier interval.
// out[m*V_+n] = (t<len[b]) ? ctx[m]@Wp[n]+bp[n] : 0,  m = b*T+t.
// ---------------------------------------------------------------------------
__global__ __launch_bounds__(256) void gemm_logits(
    const bf16* __restrict__ A, const bf16* __restrict__ Bm,
    const float* __restrict__ bias, float* __restrict__ Cout,
    const int* __restrict__ lengths)
{
    __shared__ bf16 As[2 * 128 * 32];   // 16 KB
    __shared__ bf16 Bs[2 * 256 * 32];   // 32 KB
    const int m0 = blockIdx.x * 128, n0 = blockIdx.y * 256;
    const int tid = threadIdx.x;
    const int w = tid >> 6, l = tid & 63;
    const int wm = (w >> 1) * 64, wn = (w & 1) * 128;
    const int lr = l & 15, lq = l >> 4;

    v4f acc[4][8] = {};

    for (int k0 = 0; k0 < D_; k0 += 64) {
        __syncthreads();
        #pragma unroll
        for (int c = 0; c < 4; c++) {   // A: 1024 16B units
            int u = c * 256 + tid;
            int h = u >> 9, v = u & 511;
            int row = v >> 2, kc = (v & 3) * 8;
            int u0 = c * 256 + (tid & ~63);
            GLOAD_LDS16(&A[(long)(m0 + row) * D_ + k0 + h * 32 + kc], &As[u0 * 8]);
        }
        #pragma unroll
        for (int c = 0; c < 8; c++) {   // B: 2048 16B units
            int u = c * 256 + tid;
            int h = u >> 10, v = u & 1023;
            int row = v >> 2, kc = (v & 3) * 8;
            int u0 = c * 256 + (tid & ~63);
            GLOAD_LDS16(&Bm[(long)(n0 + row) * D_ + k0 + h * 32 + kc], &Bs[u0 * 8]);
        }
        __syncthreads();
        #pragma unroll
        for (int h = 0; h < 2; h++) {
            v8bf af[4], bfv[8];
            #pragma unroll
            for (int s = 0; s < 4; s++)
                af[s] = *(const v8bf*)&As[h * 4096 + (wm + s * 16 + lr) * 32 + lq * 8];
            #pragma unroll
            for (int s = 0; s < 8; s++)
                bfv[s] = *(const v8bf*)&Bs[h * 8192 + (wn + s * 16 + lr) * 32 + lq * 8];
            #pragma unroll
            for (int i = 0; i < 4; i++)
                #pragma unroll
                for (int j = 0; j < 8; j++)
                    acc[i][j] = __builtin_amdgcn_mfma_f32_16x16x32_bf16(af[i], bfv[j], acc[i][j], 0, 0, 0);
        }
    }

    #pragma unroll
    for (int i = 0; i < 4; i++) {
        int m = m0 + wm + i * 16 + lq * 4;
        #pragma unroll
        for (int j = 0; j < 8; j++) {
            int n = n0 + wn + j * 16 + lr;
            if (n < V_) {
                float bn = bias[n];
                #pragma unroll
                for (int r = 0; r < 4; r++) {
                    int mm = m + r;
                    int t = mm % T_, b = mm / T_;
                    float o = (t < lengths[b]) ? (acc[i][j][r] + bn) : 0.f;
                    Cout[(long)mm * V_ + n] = o;
                }
            }
        }
    }
}

// ---------------------------------------------------------------------------
// Fused per-step kernel, launched T_+1 times (s = 0..T_).
// Blocks 0..255 (if s<T): LSTM step s — gates = Xpre[s] + H[s] @ W_hh^T,
//   cell update, H[s+1].  Block owns 16b x 16j x 4 gates (wave = gate).
// Blocks 256..287 (if s>=1): attention for t = s-1 — wave owns one b:
//   g = Wg@h+bg; z = wh.tanh(Vproj+g)+bh; alpha=softmax(z);
//   ctx[b*T+t] = alpha@spatial + h  (bf16).
// ---------------------------------------------------------------------------
__global__ __launch_bounds__(256) void step_attn(
    bf16* __restrict__ Hb16, const bf16* __restrict__ Whh_b,
    const float* __restrict__ Xpre, float* __restrict__ mbuf,
    const int* __restrict__ lengths,
    const bf16* __restrict__ Wg_b, const float* __restrict__ bg_pad,
    const float* __restrict__ Vproj, const float* __restrict__ wh,
    const float* __restrict__ bh_att, const bf16* __restrict__ Sp_b,
    bf16* __restrict__ ctx, int s)
{
    const int tid = threadIdx.x;
    const int w = tid >> 6, l = tid & 63;
    const int lr = l & 15, lq = l >> 4;

    __shared__ float g4[4][16][16];
    __shared__ float shh[4][512];
    __shared__ float sgv[4][64];
    __shared__ float sal[4][64];
    __shared__ float swh[64];

    if (blockIdx.x < 256) {
        if (s >= T_) return;
        const bf16* Hprev = Hb16 + (long)s * B_ * D_;
        bf16* Hnext = Hb16 + (long)(s + 1) * B_ * D_;
        const float* Xpre_t = Xpre + (long)s * B_ * NG_;
        const int b0 = (blockIdx.x & 7) * 16;
        const int j0 = (blockIdx.x >> 3) * 16;

        v4f acc = {};
        const bf16* Arow = Hprev + (long)(b0 + lr) * D_;
        const bf16* Brow = Whh_b + (long)(w * D_ + j0 + lr) * D_;
        #pragma unroll 4
        for (int kk = 0; kk < D_; kk += 32) {
            v8bf af  = *(const v8bf*)&Arow[kk + lq * 8];
            v8bf bfv = *(const v8bf*)&Brow[kk + lq * 8];
            acc = __builtin_amdgcn_mfma_f32_16x16x32_bf16(af, bfv, acc, 0, 0, 0);
        }
        #pragma unroll
        for (int r = 0; r < 4; r++)
            g4[w][lq * 4 + r][lr] = acc[r];
        __syncthreads();

        const int bi = tid >> 4, jj = tid & 15;
        const int bg = b0 + bi, jg = j0 + jj;
        const float* xp = Xpre_t + (long)bg * NG_ + jg;
        float gi = g4[0][bi][jj] + xp[0];
        float gf = g4[1][bi][jj] + xp[D_];
        float gc = g4[2][bi][jj] + xp[2 * D_];
        float go = g4[3][bi][jj] + xp[3 * D_];
        gi = 1.f / (1.f + expf(-gi));
        gf = 1.f / (1.f + expf(-gf));
        gc = tanhf(gc);
        go = 1.f / (1.f + expf(-go));
        long idx = (long)bg * D_ + jg;
        float m_old = mbuf[idx];
        float h_old = (float)Hprev[idx];
        bool active = s < lengths[bg];
        float m_new = gf * m_old + gi * gc;
        float h_new = go * tanhf(m_new);
        mbuf[idx] = active ? m_new : m_old;
        Hnext[idx] = (bf16)(active ? h_new : h_old);
    } else {
        if (s == 0) return;
        const int ab = (blockIdx.x - 256) * 4 + w;   // batch row, 0..127
        const int t = s - 1;

        // h row -> LDS (f32)
        const bf16* hrow = Hb16 + (long)s * B_ * D_ + (long)ab * D_;
        for (int d = l; d < D_; d += 64) shh[w][d] = (float)hrow[d];
        if (w == 0) swh[l] = (l < KK_) ? wh[l] : 0.f;
        __syncthreads();

        // g[j] = Wg[j,:] . h + bg[j]
        float gacc = 0.f;
        if (l < KK_) {
            const bf16* wrow = Wg_b + (long)l * D_;
            gacc = bg_pad[l];
            for (int it = 0; it < D_ / 8; it++) {
                v8bf wv = *(const v8bf*)&wrow[it * 8];
                #pragma unroll
                for (int e = 0; e < 8; e++)
                    gacc += (float)wv[e] * shh[w][it * 8 + e];
            }
        }
        sgv[w][l] = gacc;
        __syncthreads();

        // z[k'] and softmax
        float z = -1e30f;
        if (l < KK_) {
            const float* vp = Vproj + (long)(ab * KK_ + l) * NP_;
            float a = 0.f;
            for (int j = 0; j < KK_; j++)
                a += swh[j] * tanhf(vp[j] + sgv[w][j]);
            z = a + bh_att[0];
        }
        float mx = z;
        #pragma unroll
        for (int o = 32; o > 0; o >>= 1) mx = fmaxf(mx, __shfl_xor(mx, o));
        float e = (l < KK_) ? expf(z - mx) : 0.f;
        float sm = e;
        #pragma unroll
        for (int o = 32; o > 0; o >>= 1) sm += __shfl_xor(sm, o);
        sal[w][l] = e / sm;
        __syncthreads();

        // ctx = alpha @ spatial[b] + h
        const bf16* sp = Sp_b + (long)ab * KK_ * D_;
        bf16* crow = ctx + ((long)ab * T_ + t) * D_;
        for (int d = l; d < D_; d += 64) {
            float c = 0.f;
            for (int k = 0; k < KK_; k++)
                c += sal[w][k] * (float)sp[k * D_ + d];
            crow[d] = (bf16)(c + shh[w][d]);
        }
    }
}

// ---------------------------------------------------------------------------
extern "C" void kernel_launch(void* const* d_in, const int* in_sizes, int n_in,
                              void* d_out, int out_size, void* d_ws, size_t ws_size,
                              hipStream_t stream)
{
    const float* spatial  = (const float*)d_in[0];
    const float* gfeat    = (const float*)d_in[1];
    const int*   caps     = (const int*)d_in[2];
    const int*   lengths  = (const int*)d_in[3];
    const float* emb      = (const float*)d_in[4];
    const float* W_init_h = (const float*)d_in[5];
    const float* b_init_h = (const float*)d_in[6];
    const float* W_init_m = (const float*)d_in[7];
    const float* b_init_m = (const float*)d_in[8];
    const float* W_ih     = (const float*)d_in[9];
    const float* b_ih     = (const float*)d_in[10];
    const float* W_hh     = (const float*)d_in[11];
    const float* b_hh     = (const float*)d_in[12];
    const float* Wv       = (const float*)d_in[13];
    const float* bv       = (const float*)d_in[14];
    const float* Wg       = (const float*)d_in[15];
    const float* bg       = (const float*)d_in[16];
    const float* wh       = (const float*)d_in[17];
    const float* bh_att   = (const float*)d_in[18];
    const float* Wp       = (const float*)d_in[19];
    const float* bp       = (const float*)d_in[20];
    float* out = (float*)d_out;

    char* ws = (char*)d_ws;
    size_t off = 0;
    auto alloc = [&](size_t bytes) -> void* {
        off = (off + 255) & ~(size_t)255;
        void* p = ws + off;
        off += bytes;
        return p;
    };

    bf16* Wp_b    = (bf16*)alloc((size_t)VPAD * D_ * 2);
    bf16* Whh_b   = (bf16*)alloc((size_t)NG_ * D_ * 2);
    bf16* Wih_b   = (bf16*)alloc((size_t)NG_ * XK_ * 2);
    bf16* Xin_b   = (bf16*)alloc((size_t)T_ * B_ * XK_ * 2);
    bf16* Sp_b    = (bf16*)alloc((size_t)B_ * KK_ * D_ * 2);
    bf16* Wv_b    = (bf16*)alloc((size_t)NP_ * D_ * 2);
    bf16* Wg_b    = (bf16*)alloc((size_t)NP_ * D_ * 2);
    bf16* Winit2_b= (bf16*)alloc((size_t)2 * D_ * D_ * 2);
    bf16* Gf_b    = (bf16*)alloc((size_t)B_ * D_ * 2);
    float* bias_comb = (float*)alloc(NG_ * 4);
    float* bias_init = (float*)alloc(2 * D_ * 4);
    float* bv_pad    = (float*)alloc(NP_ * 4);
    float* bg_pad    = (float*)alloc(NP_ * 4);
    bf16* Hb16    = (bf16*)alloc((size_t)(T_ + 1) * B_ * D_ * 2);
    float* mbuf   = (float*)alloc((size_t)B_ * D_ * 4);
    float* Xpre   = (float*)alloc((size_t)T_ * B_ * NG_ * 4);
    float* VprojW = (float*)alloc((size_t)B_ * KK_ * NP_ * 4);
    bf16* ctx     = (bf16*)alloc((size_t)T_ * B_ * D_ * 2);

    // 1. prep / conversions
    prep_kernel<<<1024, 256, 0, stream>>>(
        spatial, gfeat, caps, emb, W_init_h, b_init_h, W_init_m, b_init_m,
        W_ih, b_ih, W_hh, b_hh, Wv, bv, Wg, bg, Wp,
        Wp_b, Whh_b, Wih_b, Xin_b, Sp_b, Wv_b, Wg_b, Winit2_b, Gf_b,
        bias_comb, bias_init, bv_pad, bg_pad);

    // 2. h0 (bf16 -> Hb16[0]) and m0 (f32 -> mbuf) in one GEMM
    gemm_bt<3><<<dim3(1, 8), 256, 0, stream>>>(Gf_b, Winit2_b, bias_init,
                                               Hb16, mbuf, B_, 2 * D_, D_, 0);

    // 3. V_proj = spatial @ Wv^T + bv  -> [B*K, 128] f32
    gemm_bt<0><<<dim3((B_ * KK_) / 128, 1), 256, 0, stream>>>(
        Sp_b, Wv_b, bv_pad, VprojW, nullptr, B_ * KK_, NP_, D_, NP_);

    // 4. Xpre = Xin @ W_ih^T + (b_ih + b_hh)  -> [T*B, 2048] f32
    gemm_bt<0><<<dim3((T_ * B_) / 128, NG_ / 128), 256, 0, stream>>>(
        Xin_b, Wih_b, bias_comb, Xpre, nullptr, T_ * B_, NG_, XK_, NG_);

    // 5. LSTM steps + pipelined attention (attn for t-1 rides step t's launch)
    for (int s = 0; s <= T_; s++) {
        step_attn<<<288, 256, 0, stream>>>(
            Hb16, Whh_b, Xpre, mbuf, lengths,
            Wg_b, bg_pad, VprojW, wh, bh_att, Sp_b, ctx, s);
    }

    // 6. logits = ctx @ Wp^T + bp, masked, -> d_out [B*T, V]
    gemm_logits<<<dim3((T_ * B_) / 128, VPAD / 256), 256, 0, stream>>>(
        ctx, Wp_b, bp, out, lengths);
}